// Round 3
// baseline (204.833 us; speedup 1.0000x reference)
//
#include <hip/hip_runtime.h>
#include <hip/hip_bf16.h>

// Problem constants (fixed by the reference)
#define T_SEQ 4096
#define C_EMB 768
#define NH_ 12
#define HS_ 64
#define B_SZ 2
#define M_TOK 8192        // B*T
#define N_QKV 2304        // 3*C

typedef __attribute__((ext_vector_type(8))) __bf16 bf16x8;
typedef __attribute__((ext_vector_type(8))) unsigned short ushort8v;
typedef __attribute__((ext_vector_type(2))) unsigned int uint2v;
typedef __attribute__((ext_vector_type(4))) float f32x4;

__device__ __forceinline__ unsigned short f2bf(float f) {
  __hip_bfloat16 h = __float2bfloat16(f);
  return __builtin_bit_cast(unsigned short, h);
}

__device__ __forceinline__ unsigned int pack2bf(float lo, float hi) {
  return ((unsigned int)f2bf(hi) << 16) | (unsigned int)f2bf(lo);
}

// XOR swizzle: row-major [R][64] bf16 tile (128 B rows). Spreads the 16B slot
// across banks per row so b128 frag reads (fixed col, rows=lane&15) are
// near-conflict-free. Must be applied on BOTH write and read.
#define KSWZ(row, bytecol) ((((row) * 128) + ((bytecol) ^ (((row) & 7) << 4))))

#define LOG2E 1.4426950408889634f

// ---------------------------------------------------------------- converts
__global__ void cvt_f32_bf16(const float* __restrict__ in,
                             unsigned short* __restrict__ out) {
  int i = (blockIdx.x * 256 + threadIdx.x) * 4;
  float4 v = *reinterpret_cast<const float4*>(&in[i]);
  ushort4 o;
  o.x = f2bf(v.x); o.y = f2bf(v.y); o.z = f2bf(v.z); o.w = f2bf(v.w);
  *reinterpret_cast<ushort4*>(&out[i]) = o;
}

// ---------------------------------------------------------------- GEMM (B^T)
// C[M][N] = A[M][K] * Bw[N][K]^T + bias.  128x128 tile, 4 waves, BK=64.
// MODE 0: A is fp32 (converted to bf16 in staging); scatter into
//         Q [bh][t][64] (scaled), K [bh][t][64], Vt [bh][d][t]
// MODE 1: A is bf16; fp32 out row-major [M][N]
template <int MODE>
__global__ __launch_bounds__(256) void gemm_bt_kernel(
    const void* __restrict__ Av, const unsigned short* __restrict__ Bw,
    const float* __restrict__ bias, unsigned short* __restrict__ qo,
    unsigned short* __restrict__ ko, unsigned short* __restrict__ vo,
    float* __restrict__ fo, int Kdim, int Ndim) {
  __shared__ unsigned short as_[128 * 72];  // +8 pad: spread banks on frag reads
  __shared__ unsigned short bs_[128 * 72];
  const int tid = threadIdx.x;
  const int lane = tid & 63;
  const int wid = tid >> 6;
  const int g = lane >> 4;
  const int l15 = lane & 15;
  const int m0 = blockIdx.y * 128;
  const int n0 = blockIdx.x * 128;
  const int wm = (wid >> 1) * 64;
  const int wn = (wid & 1) * 64;

  f32x4 acc[4][4];
#pragma unroll
  for (int i = 0; i < 4; ++i)
#pragma unroll
    for (int j = 0; j < 4; ++j) acc[i][j] = (f32x4){0.f, 0.f, 0.f, 0.f};

  for (int k0 = 0; k0 < Kdim; k0 += 64) {
#pragma unroll
    for (int it = 0; it < 4; ++it) {
      int cid = tid + it * 256;
      int r = cid >> 3, c8 = (cid & 7) << 3;
      if (MODE == 0) {
        const float* Af = (const float*)Av;
        float4 a0 = *reinterpret_cast<const float4*>(&Af[(size_t)(m0 + r) * Kdim + k0 + c8]);
        float4 a1 = *reinterpret_cast<const float4*>(&Af[(size_t)(m0 + r) * Kdim + k0 + c8 + 4]);
        ushort8v av;
        av[0] = f2bf(a0.x); av[1] = f2bf(a0.y); av[2] = f2bf(a0.z); av[3] = f2bf(a0.w);
        av[4] = f2bf(a1.x); av[5] = f2bf(a1.y); av[6] = f2bf(a1.z); av[7] = f2bf(a1.w);
        *reinterpret_cast<ushort8v*>(&as_[r * 72 + c8]) = av;
      } else {
        const unsigned short* Ab = (const unsigned short*)Av;
        *reinterpret_cast<ushort8v*>(&as_[r * 72 + c8]) =
            *reinterpret_cast<const ushort8v*>(&Ab[(size_t)(m0 + r) * Kdim + k0 + c8]);
      }
      *reinterpret_cast<ushort8v*>(&bs_[r * 72 + c8]) =
          *reinterpret_cast<const ushort8v*>(&Bw[(size_t)(n0 + r) * Kdim + k0 + c8]);
    }
    __syncthreads();
#pragma unroll
    for (int ks = 0; ks < 2; ++ks) {
      bf16x8 af[4], bfr[4];
#pragma unroll
      for (int mf = 0; mf < 4; ++mf)
        af[mf] = __builtin_bit_cast(bf16x8,
            *reinterpret_cast<const ushort8v*>(&as_[(wm + mf * 16 + l15) * 72 + ks * 32 + g * 8]));
#pragma unroll
      for (int nf = 0; nf < 4; ++nf)
        bfr[nf] = __builtin_bit_cast(bf16x8,
            *reinterpret_cast<const ushort8v*>(&bs_[(wn + nf * 16 + l15) * 72 + ks * 32 + g * 8]));
#pragma unroll
      for (int mf = 0; mf < 4; ++mf)
#pragma unroll
        for (int nf = 0; nf < 4; ++nf)
          acc[mf][nf] = __builtin_amdgcn_mfma_f32_16x16x32_bf16(
              af[mf], bfr[nf], acc[mf][nf], 0, 0, 0);
    }
    __syncthreads();
  }

#pragma unroll
  for (int mf = 0; mf < 4; ++mf)
#pragma unroll
    for (int nf = 0; nf < 4; ++nf) {
      const int n = n0 + wn + nf * 16 + l15;
      const float bval = bias[n];
      float v4[4];
#pragma unroll
      for (int r2 = 0; r2 < 4; ++r2) v4[r2] = acc[mf][nf][r2] + bval;
      const int mb = m0 + wm + mf * 16 + g * 4;   // 4-aligned row base
      if (MODE == 1) {
#pragma unroll
        for (int r2 = 0; r2 < 4; ++r2)
          fo[(size_t)(mb + r2) * Ndim + n] = v4[r2];
      } else {
        const int which = (n >= 1536) ? 2 : ((n >= 768) ? 1 : 0);
        const int c = n - which * 768;
        const int h = c >> 6, d = c & 63;
        const int bI = mb >> 12, t = mb & 4095;
        if (which == 0) {
          const size_t off = ((size_t)(bI * NH_ + h) * T_SEQ + t) * HS_ + d;
#pragma unroll
          for (int r2 = 0; r2 < 4; ++r2)
            qo[off + (size_t)r2 * HS_] = f2bf(v4[r2] * 0.125f);  // fold SCALE
        } else if (which == 1) {
          const size_t off = ((size_t)(bI * NH_ + h) * T_SEQ + t) * HS_ + d;
#pragma unroll
          for (int r2 = 0; r2 < 4; ++r2)
            ko[off + (size_t)r2 * HS_] = f2bf(v4[r2]);
        } else {
          // V transposed: Vt[bh][d][t] — 4 consecutive t → one 8B store
          const size_t off = ((size_t)(bI * NH_ + h) * HS_ + d) * T_SEQ + t;
          ushort4 o;
          o.x = f2bf(v4[0]); o.y = f2bf(v4[1]);
          o.z = f2bf(v4[2]); o.w = f2bf(v4[3]);
          *reinterpret_cast<ushort4*>(&vo[off]) = o;
        }
      }
    }
}

// ---------------------------------------------------------------- flash attn
// v3: 512 threads, 8 waves x 16 tq (QBLK=128), KV tiles of 64.
// St = mfma(K,Q) -> St[tk][tq]; per-lane softmax stats (col tq = lane&15).
// l via ones-MFMA into a rescaled accumulator; exp2+fma softmax; defer-max
// rescale (THR=8); reg-dbuf K/V staging; PV: O^T = mfma(Vt, P^T).
__global__ __launch_bounds__(512, 6) void flash_kernel(
    const unsigned short* __restrict__ Qg, const unsigned short* __restrict__ Kg,
    const unsigned short* __restrict__ Vtg, unsigned short* __restrict__ Og) {
  __shared__ __align__(16) char ksm[8192];    // K tile [64 tk][64 d], swizzled
  __shared__ __align__(16) char vtm[8192];    // Vt tile [64 d][64 tk], swizzled
  __shared__ __align__(16) char pls[16384];   // P^T per wave [16 tq][64 tk]
  const int tid = threadIdx.x;
  const int lane = tid & 63;
  const int wid = tid >> 6;        // 0..7
  const int g = lane >> 4;
  const int l15 = lane & 15;

  // balanced triple mapping: resident triple {767-c, 256+c, c} has qt-sum
  // ~const; heavy tiles dispatched first.
  const int cc = blockIdx.x & 255, kk = blockIdx.x >> 8;
  const int m = (kk == 0) ? (767 - cc) : ((kk == 1) ? (256 + cc) : cc);
  const int qt = m / 24;
  const int bh = m - qt * 24;
  const int q0 = qt * 128;
  const int b_ = bh / NH_, h_ = bh % NH_;
  const size_t kqbase = (size_t)bh * T_SEQ * HS_;
  const size_t vtbase = (size_t)bh * HS_ * T_SEQ;
  const int wq0 = wid * 16;

  // Q fragments: loop-invariant, straight from global (no LDS)
  bf16x8 qf[2];
#pragma unroll
  for (int ks = 0; ks < 2; ++ks)
    qf[ks] = __builtin_bit_cast(bf16x8,
        *reinterpret_cast<const ushort8v*>(
            &Qg[kqbase + (size_t)(q0 + wq0 + l15) * HS_ + ks * 32 + g * 8]));

  // all-ones A-fragment for the l (denominator) MFMA
  ushort8v ou;
#pragma unroll
  for (int j = 0; j < 8; ++j) ou[j] = 0x3f80;  // bf16 1.0
  const bf16x8 ones_f = __builtin_bit_cast(bf16x8, ou);

  float m_run = -1e30f;
  float ml2 = -1.4427e30f;          // m_run * LOG2E
  f32x4 oacc[4];
  f32x4 lacc = (f32x4){0.f, 0.f, 0.f, 0.f};
#pragma unroll
  for (int j = 0; j < 4; ++j) oacc[j] = (f32x4){0.f, 0.f, 0.f, 0.f};

  char* pw = pls + wid * 2048;     // this wave's P^T region

  const int nkt = 2 * qt + 2;                    // block KV-tile count
  const int myt = ((q0 + wq0 + 15) >> 6) + 1;    // this wave's needed tiles

  // staging: each of 512 threads owns one 16B chunk of K and of Vt
  const int sr = tid >> 3;                 // row 0..63
  const int sc = (tid & 7) * 16;           // byte col
  const unsigned short* kgp = &Kg[kqbase + (size_t)sr * HS_ + (sc >> 1)];
  const unsigned short* vgp = &Vtg[vtbase + (size_t)sr * T_SEQ + (sc >> 1)];

  ushort8v kreg = *reinterpret_cast<const ushort8v*>(kgp);        // tile 0
  ushort8v vreg = *reinterpret_cast<const ushort8v*>(vgp);

  for (int kt = 0; kt < nkt; ++kt) {
    __syncthreads();   // previous tile's LDS reads done
    *reinterpret_cast<ushort8v*>(ksm + KSWZ(sr, sc)) = kreg;
    *reinterpret_cast<ushort8v*>(vtm + KSWZ(sr, sc)) = vreg;
    if (kt + 1 < nkt) {          // prefetch next tile; in flight over compute
      const int k1 = (kt + 1) << 6;
      kreg = *reinterpret_cast<const ushort8v*>(kgp + (size_t)k1 * HS_);
      vreg = *reinterpret_cast<const ushort8v*>(vgp + k1);
    }
    __syncthreads();   // this tile's LDS ready

    if (kt < myt) {
      const int k0 = kt << 6;
      // ---- QK^T (swapped): St[tk][tq], col tq = l15
      f32x4 st[4];
#pragma unroll
      for (int i = 0; i < 4; ++i) st[i] = (f32x4){0.f, 0.f, 0.f, 0.f};
#pragma unroll
      for (int ks = 0; ks < 2; ++ks) {
        bf16x8 kf[4];
#pragma unroll
        for (int mf = 0; mf < 4; ++mf)
          kf[mf] = __builtin_bit_cast(bf16x8,
              *reinterpret_cast<const ushort8v*>(
                  ksm + KSWZ(mf * 16 + l15, ks * 64 + g * 16)));
#pragma unroll
        for (int mf = 0; mf < 4; ++mf)
          st[mf] = __builtin_amdgcn_mfma_f32_16x16x32_bf16(
              kf[mf], qf[ks], st[mf], 0, 0, 0);
      }

      // ---- causal mask (wave-uniform branch; ~1 diagonal tile per wave)
      if (k0 + 63 > q0 + wq0) {
        const int tq = q0 + wq0 + l15;
#pragma unroll
        for (int mf = 0; mf < 4; ++mf)
#pragma unroll
          for (int r2 = 0; r2 < 4; ++r2) {
            const int tk = k0 + mf * 16 + g * 4 + r2;
            if (tk > tq) st[mf][r2] = -1e30f;
          }
      }

      // ---- column max: max3 tree over 16 local, then cross-row shfl
      float mx = fmaxf(fmaxf(st[0][0], st[0][1]), st[0][2]);
      mx = fmaxf(fmaxf(mx, st[0][3]), st[1][0]);
      mx = fmaxf(fmaxf(mx, st[1][1]), st[1][2]);
      mx = fmaxf(fmaxf(mx, st[1][3]), st[2][0]);
      mx = fmaxf(fmaxf(mx, st[2][1]), st[2][2]);
      mx = fmaxf(fmaxf(mx, st[2][3]), st[3][0]);
      mx = fmaxf(fmaxf(mx, st[3][1]), st[3][2]);
      mx = fmaxf(mx, st[3][3]);
      mx = fmaxf(mx, __shfl_xor(mx, 16));
      mx = fmaxf(mx, __shfl_xor(mx, 32));

      // ---- defer-max: rescale only when max grew by > THR=8
      if (__any(mx > m_run + 8.f)) {
        const float mnew = fmaxf(m_run, mx);
        const float alpha = exp2f((m_run - mnew) * LOG2E);
#pragma unroll
        for (int nd = 0; nd < 4; ++nd)
#pragma unroll
          for (int r2 = 0; r2 < 4; ++r2) oacc[nd][r2] *= alpha;
#pragma unroll
        for (int r2 = 0; r2 < 4; ++r2) lacc[r2] *= alpha;
        m_run = mnew;
        ml2 = mnew * LOG2E;
      }

      // ---- P = exp2(st*LOG2E - ml2); pack bf16; write P^T to wave LDS
#pragma unroll
      for (int mf = 0; mf < 4; ++mf) {
        const float p0 = exp2f(fmaf(st[mf][0], LOG2E, -ml2));
        const float p1 = exp2f(fmaf(st[mf][1], LOG2E, -ml2));
        const float p2 = exp2f(fmaf(st[mf][2], LOG2E, -ml2));
        const float p3 = exp2f(fmaf(st[mf][3], LOG2E, -ml2));
        uint2v w;
        w.x = pack2bf(p0, p1);
        w.y = pack2bf(p2, p3);
        *reinterpret_cast<uint2v*>(pw + KSWZ(l15, mf * 32 + g * 8)) = w;
      }

      // ---- PV: O^T[d][tq] += mfma(Vt, P^T);  l via ones-MFMA
#pragma unroll
      for (int ks = 0; ks < 2; ++ks) {
        bf16x8 pf = __builtin_bit_cast(bf16x8,
            *reinterpret_cast<const ushort8v*>(
                pw + KSWZ(l15, ks * 64 + g * 16)));
        bf16x8 vt[4];
#pragma unroll
        for (int nd = 0; nd < 4; ++nd)
          vt[nd] = __builtin_bit_cast(bf16x8,
              *reinterpret_cast<const ushort8v*>(
                  vtm + KSWZ(nd * 16 + l15, ks * 64 + g * 16)));
#pragma unroll
        for (int nd = 0; nd < 4; ++nd)
          oacc[nd] = __builtin_amdgcn_mfma_f32_16x16x32_bf16(
              vt[nd], pf, oacc[nd], 0, 0, 0);
        lacc = __builtin_amdgcn_mfma_f32_16x16x32_bf16(
            ones_f, pf, lacc, 0, 0, 0);
      }
    }
  }

  // ---- epilogue: normalize per-lane (col=tq), store O^T -> Og[t][c]
  const float invl = 1.f / lacc[0];
  const int t = q0 + wq0 + l15;
#pragma unroll
  for (int nd = 0; nd < 4; ++nd) {
    ushort4 o;
    o.x = f2bf(oacc[nd][0] * invl);
    o.y = f2bf(oacc[nd][1] * invl);
    o.z = f2bf(oacc[nd][2] * invl);
    o.w = f2bf(oacc[nd][3] * invl);
    *reinterpret_cast<ushort4*>(
        &Og[((size_t)(b_ * T_SEQ + t)) * C_EMB + h_ * 64 + nd * 16 + g * 4]) = o;
  }
}

// ---------------------------------------------------------------- launch
extern "C" void kernel_launch(void* const* d_in, const int* in_sizes, int n_in,
                              void* d_out, int out_size, void* d_ws, size_t ws_size,
                              hipStream_t stream) {
  const float* x = (const float*)d_in[0];
  const float* w_attn = (const float*)d_in[1];
  const float* b_attn = (const float*)d_in[2];
  const float* w_proj = (const float*)d_in[3];
  const float* b_proj = (const float*)d_in[4];
  float* out = (float*)d_out;

  char* ws = (char*)d_ws;
  size_t off = 0;
  auto carve = [&](size_t bytes) -> void* {
    void* p = ws + off;
    off += (bytes + 255) & ~(size_t)255;
    return p;
  };
  unsigned short* wab = (unsigned short*)carve((size_t)N_QKV * C_EMB * 2);
  unsigned short* wpb = (unsigned short*)carve((size_t)C_EMB * C_EMB * 2);
  unsigned short* Qb = (unsigned short*)carve((size_t)B_SZ * NH_ * T_SEQ * HS_ * 2);
  unsigned short* Kb = (unsigned short*)carve((size_t)B_SZ * NH_ * T_SEQ * HS_ * 2);
  unsigned short* Vtb = (unsigned short*)carve((size_t)B_SZ * NH_ * T_SEQ * HS_ * 2);
  unsigned short* Ob = (unsigned short*)carve((size_t)M_TOK * C_EMB * 2);

  cvt_f32_bf16<<<1728, 256, 0, stream>>>(w_attn, wab);   // 2304*768
  cvt_f32_bf16<<<576, 256, 0, stream>>>(w_proj, wpb);    // 768*768

  gemm_bt_kernel<0><<<dim3(N_QKV / 128, M_TOK / 128), 256, 0, stream>>>(
      x, wab, b_attn, Qb, Kb, Vtb, nullptr, C_EMB, N_QKV);

  flash_kernel<<<dim3(768), 512, 0, stream>>>(Qb, Kb, Vtb, Ob);

  gemm_bt_kernel<1><<<dim3(C_EMB / 128, M_TOK / 128), 256, 0, stream>>>(
      Ob, wpb, b_proj, nullptr, nullptr, nullptr, out, C_EMB, C_EMB);
}